// Round 2
// baseline (79.218 us; speedup 1.0000x reference)
//
#include <hip/hip_runtime.h>

// PixelVectorExtractor: one transformer encoder layer over per-pixel 7x7
// windows in a 30x30 canvas (S=900, D=11). Structure exploited:
//  - only 49/900 rows nonzero; 851 zero rows share ONE output vector
//    (row 49 = zero query -> uniform attention; +851 ones in the denom).
//  - grid is hard-capped at 256 blocks (one coupled attention per pixel)
//    = 1 block/CU -> zero inter-block TLP. Time == one block's serial
//    chain, so v7 minimizes the chain.
// v7: shuffle-ized dataflow. Row = 16-lane group (13 waves / 50 rows).
//  - seq/q/x1n broadcast via __shfl within the group (no LDS).
//  - softmax numerator + FF-out computed as 11 per-lane partials over the
//    lane's own e_t / h_f columns, then 4-step butterfly reduce: every
//    lane gets the full 11-vector in regs; out-proj consumes it directly.
//  - LDS buffers remaining: weights, K, V (cross-wave), final sR.
//    3 block barriers, 0 wave fences, ~60 LDS wave-instrs/wave (was ~118),
//    all reads are 16-address broadcasts at 48B stride (<=2-way, free).

#define D 11
#define ROWP 12      // padded row length (3 x float4)
#define NW 49
#define NR 50
#define FFD 64
#define CIN 10
#define SEQ 900
#define NB 256
#define TPB 832      // 13 waves; row r = tid>>4 (r<50), d = tid&15

#define FMA11(P, E, A0, A1, A2) \
    P[0] += (E)*(A0).x; P[1] += (E)*(A0).y; P[2] += (E)*(A0).z; P[3] += (E)*(A0).w; \
    P[4] += (E)*(A1).x; P[5] += (E)*(A1).y; P[6] += (E)*(A1).z; P[7] += (E)*(A1).w; \
    P[8] += (E)*(A2).x; P[9] += (E)*(A2).y; P[10] += (E)*(A2).z;

#define DOT11(Q, A0, A1, A2) \
    ((Q)[0]*(A0).x + (Q)[1]*(A0).y + (Q)[2]*(A0).z + (Q)[3]*(A0).w + \
     (Q)[4]*(A1).x + (Q)[5]*(A1).y + (Q)[6]*(A1).z + (Q)[7]*(A1).w + \
     (Q)[8]*(A2).x + (Q)[9]*(A2).y + (Q)[10]*(A2).z)

#define RED16(X) \
    X += __shfl_xor(X, 8, 16); X += __shfl_xor(X, 4, 16); \
    X += __shfl_xor(X, 2, 16); X += __shfl_xor(X, 1, 16);

__global__ __launch_bounds__(TPB) void pve_kernel(
    const float* __restrict__ gx,     // [10,16,16]
    const float* __restrict__ gWqkv,  // [33,11]
    const float* __restrict__ gWo,    // [11,11]
    const float* __restrict__ gW1,    // [64,11]
    const float* __restrict__ gW2,    // [11,64]
    const float* __restrict__ gln1,   // [11]
    const float* __restrict__ gln2,   // [11]
    float* __restrict__ out)          // [256,10,900]
{
    __shared__ __align__(16) float sQ[33 * ROWP];     // Wqkv rows, padded
    __shared__ __align__(16) float sWo[D * ROWP];
    __shared__ __align__(16) float sW1[FFD * ROWP];   // W1 rows [ff][dd]
    __shared__ __align__(16) float sW2t[FFD * ROWP];  // W2 transposed [f][dd]
    __shared__ __align__(16) float sK[NW][ROWP];
    __shared__ __align__(16) float sV[NW][ROWP];
    __shared__ __align__(16) float sR[NR][ROWP];

    const int tid = threadIdx.x;
    const int b = blockIdx.x;
    const int h = b >> 4;
    const int w = b & 15;

    const int r = tid >> 4;          // row group, valid when < 50
    const int d = tid & 15;          // lane-in-row; real dims d < 11
    const bool rowv = (r < NR);
    const bool dv = (d < D);

    // ---- phase 0a: stage ONLY what phase 1 needs (sQ) + input elem ----
    for (int i = tid; i < 33 * ROWP; i += TPB) {
        const int rr = i / ROWP, cc = i - rr * ROWP;
        sQ[i] = (cc < D) ? gWqkv[rr * D + cc] : 0.f;
    }
    float lnw1 = 0.f, lnw2 = 0.f;
    if (dv) { lnw1 = gln1[d]; lnw2 = gln2[d]; }

    float xin = 0.f;                 // this lane's input element (reg only)
    if (rowv && dv && r < NW) {
        const int i7 = r / 7, j7 = r - i7 * 7;
        const int y = h + i7, xx = w + j7;
        const bool inter = (y >= 3) && (y < 19) && (xx >= 3) && (xx < 19);
        const int base = inter ? ((y - 3) * 16 + (xx - 3)) : 0;
        if (d < CIN) xin = inter ? gx[d * 256 + base] : 0.0f;
        else         xin = inter ? 0.0f : 1.0f;          // mask channel
    }
    __syncthreads();                 // barrier 1: sQ staged

    // ---- phase 1: qkv projection from shuffled seq; stage other weights ----
    float aq = 0.f;
    if (rowv) {
        float sx[11];
        #pragma unroll
        for (int dd = 0; dd < 11; ++dd) sx[dd] = __shfl(xin, dd, 16);
        if (dv) {
            const float4* qa = (const float4*)&sQ[d * ROWP];
            const float4* ka = (const float4*)&sQ[(D + d) * ROWP];
            const float4* va = (const float4*)&sQ[(2 * D + d) * ROWP];
            const float4 q0 = qa[0], q1 = qa[1], q2 = qa[2];
            const float4 k0 = ka[0], k1 = ka[1], k2 = ka[2];
            const float4 v0 = va[0], v1 = va[1], v2 = va[2];
            aq = DOT11(sx, q0, q1, q2);
            const float ak = DOT11(sx, k0, k1, k2);
            const float av = DOT11(sx, v0, v1, v2);
            if (r < NW) { sK[r][d] = ak; sV[r][d] = av; }
        }
    }
    // stage sWo / sW1 / sW2t concurrently with the projection (used post-B2)
    for (int i = tid; i < D * ROWP; i += TPB) {
        const int rr = i / ROWP, cc = i - rr * ROWP;
        sWo[i] = (cc < D) ? gWo[rr * D + cc] : 0.f;
    }
    for (int i = tid; i < FFD * ROWP; i += TPB) {
        const int rr = i / ROWP, cc = i - rr * ROWP;
        sW1[i] = (cc < D) ? gW1[rr * D + cc] : 0.f;
    }
    for (int i = tid; i < FFD * ROWP; i += TPB) {
        const int ff = i / ROWP, cc = i - ff * ROWP;
        sW2t[i] = (cc < D) ? gW2[cc * FFD + ff] : 0.f;
    }
    __syncthreads();                 // barrier 2: sK/sV + all weights ready

    // ---- phase 2: scores + exp + denom; e_t stays in regs ----
    float den = 851.0f;
    float ev[4] = {0.f, 0.f, 0.f, 0.f};
    if (rowv) {
        const float scale = 0.30151134457776363f;       // 1/sqrt(11)
        float q[11];
        #pragma unroll
        for (int dd = 0; dd < 11; ++dd) q[dd] = __shfl(aq, dd, 16);
        #pragma unroll
        for (int it = 0; it < 4; ++it) {
            const int tt = d + (it << 4);
            if (tt < NW) {
                const float4* kp = (const float4*)&sK[tt][0];
                const float4 k0 = kp[0], k1 = kp[1], k2 = kp[2];
                const float s = DOT11(q, k0, k1, k2);
                ev[it] = __expf(s * scale);
            }
        }
        float ps = ev[0] + ev[1] + ev[2] + ev[3];
        RED16(ps);
        den += ps;                   // every lane of the row has den in reg
    }

    // ---- phase 3: numerator = sum_t e_t * V[t][:] as lane partials ----
    float num[11] = {0.f,0.f,0.f,0.f,0.f,0.f,0.f,0.f,0.f,0.f,0.f};
    if (rowv) {
        #pragma unroll
        for (int it = 0; it < 4; ++it) {
            const int tt = d + (it << 4);
            if (tt < NW) {
                const float4* vp = (const float4*)&sV[tt][0];
                const float4 v0 = vp[0], v1 = vp[1], v2 = vp[2];
                const float e = ev[it];
                FMA11(num, e, v0, v1, v2);
            }
        }
        #pragma unroll
        for (int dd = 0; dd < 11; ++dd) { RED16(num[dd]); }
        // all 16 lanes now hold the full 11-dim numerator in regs
    }

    // ---- phase 4+5: out-proj + residual + LN1, all in registers ----
    float x1 = 0.f;
    if (rowv && dv) {
        const float4* wp = (const float4*)&sWo[d * ROWP];
        const float4 w0 = wp[0], w1 = wp[1], w2 = wp[2];
        const float acc = DOT11(num, w0, w1, w2);
        x1 = xin + acc / den;
    }
    {   // LN1 stats over the 16-lane group (d>=11 contribute 0)
        float s1 = x1, s2 = x1 * x1;
        RED16(s1); RED16(s2);
        const float m   = s1 * (1.0f / 11.0f);
        const float var = s2 * (1.0f / 11.0f) - m * m;
        x1 = (x1 - m) * rsqrtf(var + 1e-5f) * lnw1;      // x1 is now x1n
    }

    // ---- phase 6: FF hidden; x1n broadcast via shfl, h stays in regs ----
    float hh[4] = {0.f, 0.f, 0.f, 0.f};
    if (rowv) {
        float xb[11];
        #pragma unroll
        for (int dd = 0; dd < 11; ++dd) xb[dd] = __shfl(x1, dd, 16);
        #pragma unroll
        for (int it = 0; it < 4; ++it) {
            const int ff = d + (it << 4);
            const float4* wp = (const float4*)&sW1[ff * ROWP];
            const float4 w0 = wp[0], w1 = wp[1], w2 = wp[2];
            hh[it] = fmaxf(DOT11(xb, w0, w1, w2), 0.0f);
        }
    }

    // ---- phase 7: FF out as lane partials over own h columns ----
    float p2[11] = {0.f,0.f,0.f,0.f,0.f,0.f,0.f,0.f,0.f,0.f,0.f};
    if (rowv) {
        #pragma unroll
        for (int it = 0; it < 4; ++it) {
            const int f = d + (it << 4);
            const float4* wp = (const float4*)&sW2t[f * ROWP];
            const float4 w0 = wp[0], w1 = wp[1], w2 = wp[2];
            const float e = hh[it];
            FMA11(p2, e, w0, w1, w2);
        }
        #pragma unroll
        for (int dd = 0; dd < 11; ++dd) { RED16(p2[dd]); }
    }
    float ysel = 0.f;
    #pragma unroll
    for (int dd = 0; dd < 11; ++dd) ysel = (d == dd) ? p2[dd] : ysel;
    const float y = x1 + ysel;       // pad lanes: x1n==0 (lnw1=0), ysel==0

    // ---- phase 8: LN2 in registers, write final rows ----
    {
        float s1 = y, s2 = y * y;
        RED16(s1); RED16(s2);
        const float m   = s1 * (1.0f / 11.0f);
        const float var = s2 * (1.0f / 11.0f) - m * m;
        if (rowv && dv) sR[r][d] = (y - m) * rsqrtf(var + 1e-5f) * lnw2;
    }
    __syncthreads();                 // barrier 3: sR complete for epilogue

    // ---- phase 9: epilogue, out[b,c,s] as float4 (2250 per block) ----
    float4* ob4 = (float4*)(out + b * (CIN * SEQ));
    #pragma unroll
    for (int k = 0; k < 3; ++k) {
        const int qi = tid + k * TPB;
        if (qi < 2250) {
            const int c  = qi / 225;             // 225 float4 per channel
            const int s0 = (qi - c * 225) * 4;
            float4 v4;
            float* pv = (float*)&v4;
            #pragma unroll
            for (int u = 0; u < 4; ++u) {
                const int s = s0 + u;
                const int i = s / 30;
                const int j = s - i * 30;
                pv[u] = (i < 7 && j < 7) ? sR[i * 7 + j][c] : sR[NW][c];
            }
            ob4[qi] = v4;
        }
    }
}

extern "C" void kernel_launch(void* const* d_in, const int* in_sizes, int n_in,
                              void* d_out, int out_size, void* d_ws, size_t ws_size,
                              hipStream_t stream) {
    (void)in_sizes; (void)n_in; (void)out_size; (void)d_ws; (void)ws_size;
    const float* x    = (const float*)d_in[0];
    const float* Wqkv = (const float*)d_in[1];
    const float* Wo   = (const float*)d_in[2];
    const float* W1   = (const float*)d_in[3];
    const float* W2   = (const float*)d_in[4];
    const float* ln1  = (const float*)d_in[5];
    const float* ln2  = (const float*)d_in[6];
    pve_kernel<<<NB, TPB, 0, stream>>>(x, Wqkv, Wo, W1, W2, ln1, ln2,
                                       (float*)d_out);
}

// Round 3
// 76.233 us; speedup vs baseline: 1.0392x; 1.0392x over previous
//
#include <hip/hip_runtime.h>

// PixelVectorExtractor: one transformer encoder layer over per-pixel 7x7
// windows in a 30x30 canvas (S=900, D=11). Structure exploited:
//  - only 49/900 rows nonzero; 851 zero rows share ONE output vector
//    (row 49 = zero query -> uniform attention; +851 ones in the denom).
//  - grid hard-capped at 256 blocks = 1 block/CU -> no inter-block TLP.
// v8: v6 geometry (832 thr, 16-lane row groups, 3 block barriers) with the
// LDS pipe cut down. Lesson from v7: __shfl == ds_bpermute == LDS pipe.
// DPP (row_mirror/half_mirror/quad_perm on v_add_f32) is VALU-pipe and
// leaves the full sum in ALL 16 lanes -> partial-FMA phases become free:
//  - softmax numerator + FF-out as per-lane FMA11 partials + DPP reduce
//    (kills sE/sVt/sNum/sH round trips entirely).
//  - den/LN1/LN2 reductions via DPP (20 ds_swizzle -> 0).
//  - DOT11 ignores the pad element -> no pad zeroing anywhere.
// Per-wave LDS instrs ~121 -> ~78, swizzles 20 -> 0.

#define D 11
#define ROWP 12      // padded row length (3 x float4)
#define NW 49
#define NR 50
#define FFD 64
#define CIN 10
#define SEQ 900
#define NB 256
#define TPB 832      // 13 waves; group g = tid>>4 = row, lane d = tid&15

// 16-lane butterfly sum, pure VALU (DPP). All 16 lanes get the total.
__device__ __forceinline__ float red16(float v) {
    v += __int_as_float(__builtin_amdgcn_update_dpp(
        0, __float_as_int(v), 0x140, 0xf, 0xf, true));   // row_mirror
    v += __int_as_float(__builtin_amdgcn_update_dpp(
        0, __float_as_int(v), 0x141, 0xf, 0xf, true));   // row_half_mirror
    v += __int_as_float(__builtin_amdgcn_update_dpp(
        0, __float_as_int(v), 0x4E, 0xf, 0xf, true));    // quad_perm [2,3,0,1]
    v += __int_as_float(__builtin_amdgcn_update_dpp(
        0, __float_as_int(v), 0xB1, 0xf, 0xf, true));    // quad_perm [1,0,3,2]
    return v;
}

#define DOT11V(A0, A1, A2, B0, B1, B2) \
    ((A0).x*(B0).x + (A0).y*(B0).y + (A0).z*(B0).z + (A0).w*(B0).w + \
     (A1).x*(B1).x + (A1).y*(B1).y + (A1).z*(B1).z + (A1).w*(B1).w + \
     (A2).x*(B2).x + (A2).y*(B2).y + (A2).z*(B2).z)

#define DOT11A(Q, A0, A1, A2) \
    ((Q)[0]*(A0).x + (Q)[1]*(A0).y + (Q)[2]*(A0).z + (Q)[3]*(A0).w + \
     (Q)[4]*(A1).x + (Q)[5]*(A1).y + (Q)[6]*(A1).z + (Q)[7]*(A1).w + \
     (Q)[8]*(A2).x + (Q)[9]*(A2).y + (Q)[10]*(A2).z)

#define FMA11(P, E, A0, A1, A2) \
    P[0] += (E)*(A0).x; P[1] += (E)*(A0).y; P[2] += (E)*(A0).z; P[3] += (E)*(A0).w; \
    P[4] += (E)*(A1).x; P[5] += (E)*(A1).y; P[6] += (E)*(A1).z; P[7] += (E)*(A1).w; \
    P[8] += (E)*(A2).x; P[9] += (E)*(A2).y; P[10] += (E)*(A2).z;

__device__ __forceinline__ void wave_sync() {
    __builtin_amdgcn_wave_barrier();
    asm volatile("s_waitcnt lgkmcnt(0)" ::: "memory");
    __builtin_amdgcn_wave_barrier();
}

__global__ __launch_bounds__(TPB) void pve_kernel(
    const float* __restrict__ gx,     // [10,16,16]
    const float* __restrict__ gWqkv,  // [33,11]
    const float* __restrict__ gWo,    // [11,11]
    const float* __restrict__ gW1,    // [64,11]
    const float* __restrict__ gW2,    // [11,64]
    const float* __restrict__ gln1,   // [11]
    const float* __restrict__ gln2,   // [11]
    float* __restrict__ out)          // [256,10,900]
{
    __shared__ __align__(16) float sQ[33 * ROWP];     // Wqkv rows
    __shared__ __align__(16) float sWo[D * ROWP];
    __shared__ __align__(16) float sW1[FFD * ROWP];   // W1 rows [f][d]
    __shared__ __align__(16) float sW2t[FFD * ROWP];  // W2 transposed [f][d]
    __shared__ __align__(16) float sSeq[NR][ROWP];
    __shared__ __align__(16) float sK[NW][ROWP];
    __shared__ __align__(16) float sV[NW][ROWP];
    __shared__ __align__(16) float sQr[NR][ROWP];
    __shared__ __align__(16) float sR[NR][ROWP];

    const int tid = threadIdx.x;
    const int b = blockIdx.x;
    const int h = b >> 4;
    const int w = b & 15;

    const int r = tid >> 4;          // row group, valid when < 50
    const int d = tid & 15;          // lane-in-row; real dims d < 11
    const bool rowv = (r < NR);
    const bool dv = (d < D);

    // ---- phase 0: stage all weights + seq rows ----
    for (int i = tid; i < 33 * ROWP; i += TPB) {
        const int rr = i / ROWP, cc = i - rr * ROWP;
        sQ[i] = (cc < D) ? gWqkv[rr * D + cc] : 0.f;
    }
    for (int i = tid; i < D * ROWP; i += TPB) {
        const int rr = i / ROWP, cc = i - rr * ROWP;
        sWo[i] = (cc < D) ? gWo[rr * D + cc] : 0.f;
    }
    for (int i = tid; i < FFD * ROWP; i += TPB) {
        const int rr = i / ROWP, cc = i - rr * ROWP;
        sW1[i] = (cc < D) ? gW1[rr * D + cc] : 0.f;
    }
    for (int i = tid; i < FFD * ROWP; i += TPB) {
        const int ff = i / ROWP, cc = i - ff * ROWP;
        sW2t[i] = (cc < D) ? gW2[cc * FFD + ff] : 0.f;
    }
    float lnw1 = 0.f, lnw2 = 0.f;
    if (dv) { lnw1 = gln1[d]; lnw2 = gln2[d]; }

    float xin = 0.f;                 // this lane's input element (regs)
    if (rowv && dv) {
        if (r < NW) {
            const int i7 = r / 7, j7 = r - i7 * 7;
            const int y = h + i7, xx = w + j7;
            const bool inter = (y >= 3) && (y < 19) && (xx >= 3) && (xx < 19);
            const int base = inter ? ((y - 3) * 16 + (xx - 3)) : 0;
            if (d < CIN) xin = inter ? gx[d * 256 + base] : 0.0f;
            else         xin = inter ? 0.0f : 1.0f;      // mask channel
        }
        sSeq[r][d] = xin;            // row 49 writes zeros; no pads needed
    }
    __syncthreads();                 // barrier 1: staging complete

    // ---- phase 1: qkv projection (per-lane dots, DOT11 -> no pads) ----
    if (rowv && dv) {
        const float4* sv = (const float4*)&sSeq[r][0];
        const float4 s0 = sv[0], s1 = sv[1], s2 = sv[2];
        const float4* qa = (const float4*)&sQ[d * ROWP];
        const float4* ka = (const float4*)&sQ[(D + d) * ROWP];
        const float4* va = (const float4*)&sQ[(2 * D + d) * ROWP];
        sQr[r][d] = DOT11V(s0, s1, s2, qa[0], qa[1], qa[2]);
        if (r < NW) {
            sK[r][d] = DOT11V(s0, s1, s2, ka[0], ka[1], ka[2]);
            sV[r][d] = DOT11V(s0, s1, s2, va[0], va[1], va[2]);
        }
    }
    __syncthreads();                 // barrier 2: sK/sV/sQr cross-wave ready

    // ---- phase 2: scores + exp + denom (e_t stays in regs) ----
    float den = 851.0f;
    float ev[4] = {0.f, 0.f, 0.f, 0.f};
    float num[11] = {0.f,0.f,0.f,0.f,0.f,0.f,0.f,0.f,0.f,0.f,0.f};
    float x1 = 0.f;
    if (rowv) {
        const float scale = 0.30151134457776363f;       // 1/sqrt(11)
        const float4* qv = (const float4*)&sQr[r][0];
        const float4 q0 = qv[0], q1 = qv[1], q2 = qv[2];
        #pragma unroll
        for (int it = 0; it < 4; ++it) {
            const int tt = d + (it << 4);
            if (tt < NW) {
                const float4* kp = (const float4*)&sK[tt][0];
                const float s = DOT11V(q0, q1, q2, kp[0], kp[1], kp[2]);
                ev[it] = __expf(s * scale);
            }
        }
        den += red16(ev[0] + ev[1] + ev[2] + ev[3]);     // all lanes have den

        // ---- phase 3: numerator partials over own key columns + DPP ----
        #pragma unroll
        for (int it = 0; it < 4; ++it) {
            const int tt = d + (it << 4);
            if (tt < NW) {
                const float4* vp = (const float4*)&sV[tt][0];
                const float4 v0 = vp[0], v1 = vp[1], v2 = vp[2];
                const float e = ev[it];
                FMA11(num, e, v0, v1, v2);
            }
        }
        #pragma unroll
        for (int dd = 0; dd < 11; ++dd) num[dd] = red16(num[dd]);
        // all 16 lanes hold the full 11-dim numerator in regs

        // ---- phase 4+5: out-proj + residual + LN1, in registers ----
        if (dv) {
            const float4* wp = (const float4*)&sWo[d * ROWP];
            x1 = xin + DOT11A(num, wp[0], wp[1], wp[2]) / den;
        }
        float s1 = red16(x1), s2 = red16(x1 * x1);       // d>=11 contribute 0
        const float m   = s1 * (1.0f / 11.0f);
        const float var = s2 * (1.0f / 11.0f) - m * m;
        x1 = (x1 - m) * rsqrtf(var + 1e-5f) * lnw1;      // x1 is now x1n
        if (dv) sQr[r][d] = x1;      // reuse sQr as x1n broadcast buffer
    }
    wave_sync();                     // wave-local: x1n write -> read

    // ---- phase 6: FF hidden, h stays in regs ----
    float hh[4] = {0.f, 0.f, 0.f, 0.f};
    float p2[11] = {0.f,0.f,0.f,0.f,0.f,0.f,0.f,0.f,0.f,0.f,0.f};
    float y = 0.f;
    if (rowv) {
        const float4* xv = (const float4*)&sQr[r][0];
        const float4 xa = xv[0], xb = xv[1], xc = xv[2];
        #pragma unroll
        for (int it = 0; it < 4; ++it) {
            const int ff = d + (it << 4);
            const float4* wp = (const float4*)&sW1[ff * ROWP];
            hh[it] = fmaxf(DOT11V(xa, xb, xc, wp[0], wp[1], wp[2]), 0.0f);
        }

        // ---- phase 7: FF out partials over own f columns + DPP ----
        #pragma unroll
        for (int it = 0; it < 4; ++it) {
            const int ff = d + (it << 4);
            const float4* wp = (const float4*)&sW2t[ff * ROWP];
            const float4 w0 = wp[0], w1 = wp[1], w2 = wp[2];
            const float e = hh[it];
            FMA11(p2, e, w0, w1, w2);
        }
        #pragma unroll
        for (int dd = 0; dd < 11; ++dd) p2[dd] = red16(p2[dd]);
        float ysel = 0.f;
        #pragma unroll
        for (int dd = 0; dd < 11; ++dd) ysel = (d == dd) ? p2[dd] : ysel;
        y = x1 + ysel;               // pad lanes: x1n==0 (lnw1=0), ysel==0

        // ---- phase 8: LN2 in registers, write final rows ----
        float s1 = red16(y), s2 = red16(y * y);
        const float m   = s1 * (1.0f / 11.0f);
        const float var = s2 * (1.0f / 11.0f) - m * m;
        if (dv) sR[r][d] = (y - m) * rsqrtf(var + 1e-5f) * lnw2;
    }
    __syncthreads();                 // barrier 3: sR complete for epilogue

    // ---- phase 9: epilogue, out[b,c,s] as float4 (2250 per block) ----
    float4* ob4 = (float4*)(out + b * (CIN * SEQ));
    #pragma unroll
    for (int k = 0; k < 3; ++k) {
        const int qi = tid + k * TPB;
        if (qi < 2250) {
            const int c  = qi / 225;             // 225 float4 per channel
            const int s0 = (qi - c * 225) * 4;
            float4 v4;
            float* pv = (float*)&v4;
            #pragma unroll
            for (int u = 0; u < 4; ++u) {
                const int s = s0 + u;
                const int i = s / 30;
                const int j = s - i * 30;
                pv[u] = (i < 7 && j < 7) ? sR[i * 7 + j][c] : sR[NW][c];
            }
            ob4[qi] = v4;
        }
    }
}

extern "C" void kernel_launch(void* const* d_in, const int* in_sizes, int n_in,
                              void* d_out, int out_size, void* d_ws, size_t ws_size,
                              hipStream_t stream) {
    (void)in_sizes; (void)n_in; (void)out_size; (void)d_ws; (void)ws_size;
    const float* x    = (const float*)d_in[0];
    const float* Wqkv = (const float*)d_in[1];
    const float* Wo   = (const float*)d_in[2];
    const float* W1   = (const float*)d_in[3];
    const float* W2   = (const float*)d_in[4];
    const float* ln1  = (const float*)d_in[5];
    const float* ln2  = (const float*)d_in[6];
    pve_kernel<<<NB, TPB, 0, stream>>>(x, Wqkv, Wo, W1, W2, ln1, ln2,
                                       (float*)d_out);
}